// Round 19
// baseline (120.612 us; speedup 1.0000x reference)
//
#include <hip/hip_runtime.h>
#include <stdint.h>

#define N_PROP 100000
#define N_LAB  256
#define NW     8                      // 256 bits / 32
#define CHUNK  256
#define NCHUNK 391                    // ceil(100000/256)
#define NCH_P  392                    // padded stride for transposed chunkOR
#define N_PAD  (NCHUNK * CHUNK)       // 100096
#define RANK_BLOCKS 128

// d_ws byte offsets
#define OFF_MASKS   0
#define OFF_CHUNKOR (N_PAD * NW * 4)                   // 3,203,072
#define OFF_KEYS    (OFF_CHUNKOR + NCHUNK * NW * 4)    // 3,215,584
#define OFF_TPCNT   (OFF_KEYS + N_LAB * 8)
#define OFF_CTRL    (OFF_TPCNT + 16)
// ctrl ints: [0]=scan-done flag, [1]=AP ticket, [2..3]=spare, [4..260]=hist.
// ALL zeroed by k_masks block 0 (k_masks completes before k_scanrank starts;
// pattern field-proven R17/R18, absmax 0.0).
#define CTRL_INTS 261

// first pending label from 4 x u64 pending words (-1 if none)
#define FIRST_PEND(j_i, w0, w1, w2, w3)         \
  {                                             \
    j_i = -1;                                   \
    if (w3) j_i = 192 + (__ffsll(w3) - 1);      \
    if (w2) j_i = 128 + (__ffsll(w2) - 1);      \
    if (w1) j_i = 64 + (__ffsll(w1) - 1);       \
    if (w0) j_i = (__ffsll(w0) - 1);            \
  }

// ---------------------------------------------------------------------------
// Kernel 1 (R15-R18, field-proven bit-exact): per-proposal IoU>0.5 masks +
// per-chunk OR. 512 threads: 2 threads/proposal, 128 labels each (disjoint
// half-mask uint4 stores). Block 0 zeroes the ctrl block.
//
// EXACT div-free predicate (validated absmax 0.0 in R15-R18): reference
// computes fl(i/u) > 0.5 with i>=0, u>0.
//   fl(r) > 0.5  <=>  r > 0.5 + 2^-26  <=>  2i - u > u * 2^-25 (exact reals)
// i <= blen <= u (RN monotone). For i in [u/4, u]: i - u/2 is Sterbenz-exact
// so fma(2,i,-u) is EXACT; u*2^-25 is an exact exponent shift; compare exact.
// For i < u/4: lhs <= -u/2 < rhs: false, matching r < 0.5.
// ---------------------------------------------------------------------------
__global__ __launch_bounds__(512) void k_masks(
    const float* __restrict__ prop, const float* __restrict__ lab,
    uint32_t* __restrict__ masks, uint32_t* __restrict__ chunkOR,
    int* __restrict__ ctrl) {
  __shared__ float4 s_lab[N_LAB];     // (bmin, bmax, blen, 0)
  __shared__ uint32_t s_or[NW];
  const int t = threadIdx.x;
  const int h = t >> 8;               // label half: 0 -> [0,128), 1 -> [128,256)
  const int q = t & 255;              // proposal slot within chunk
  if (t < N_LAB) {
    const float bmn = lab[2 * t], bmx = lab[2 * t + 1];
    s_lab[t] = make_float4(bmn, bmx, bmx - bmn, 0.0f);
  }
  if (t < NW) s_or[t] = 0u;
  if (blockIdx.x == 0) {
    for (int z = t; z < CTRL_INTS; z += 512) ctrl[z] = 0;
  }
  __syncthreads();

  const int i = blockIdx.x * 256 + q;  // < N_PAD always
  uint32_t m0 = 0u, m1 = 0u, m2 = 0u, m3 = 0u;

  if (i < N_PROP) {
    const float ps = prop[3 * i + 1], pe = prop[3 * i + 2];
    const float amin = ps / 25.0f;     // IEEE div, as reference
    const float amax = pe / 25.0f;
    const float alen = amax - amin;
    const int j0 = h << 7;
#pragma unroll 4
    for (int jj = 0; jj < 128; ++jj) {
      const float4 L = s_lab[j0 + jj];
      float inter = fminf(amax, L.y) - fmaxf(amin, L.x);
      inter = fmaxf(inter, 0.0f);
      const float uni = (alen - inter) + L.z;
      const bool pred =
          __builtin_fmaf(2.0f, inter, -uni) > uni * 0x1p-25f;  // exact
      if (pred) {
        const uint32_t b = 1u << (jj & 31);
        const int w = jj >> 5;
        m0 |= (w == 0) ? b : 0u;  m1 |= (w == 1) ? b : 0u;
        m2 |= (w == 2) ? b : 0u;  m3 |= (w == 3) ? b : 0u;
      }
    }
  }

  // disjoint half-mask store (words h*4 .. h*4+3); pad rows stay zero
  *reinterpret_cast<uint4*>(&masks[(size_t)i * NW + h * 4]) =
      make_uint4(m0, m1, m2, m3);

  if (m0 | m1 | m2 | m3) {
    const int wb = h * 4;
    if (m0) atomicOr(&s_or[wb + 0], m0);
    if (m1) atomicOr(&s_or[wb + 1], m1);
    if (m2) atomicOr(&s_or[wb + 2], m2);
    if (m3) atomicOr(&s_or[wb + 3], m3);
  }
  __syncthreads();
  if (t < NW) chunkOR[blockIdx.x * NW + t] = s_or[t];
}

// ---------------------------------------------------------------------------
// Kernel 2: block 0 = exact sequential greedy scan (wave 0, batch-commit +
// lazy stale-check, byte-identical to R18's proven drain) + TP key sort,
// then release-flag. Blocks 1..127 poll with s_sleep(16) (~1024 clocks =
// ~1.7us at idle clock -- R15's failure was s_sleep(127) = ~13.5us/poll at
// the DVFS floor, gating the AP fan-in on worst-case waker jitter; 127
// pollers at ~0.6 loads/us each = ~75 loads/us total, no line hammering).
// Then all 128 blocks run the rank histogram + last-block AP fan-in
// (byte-identical to R18's proven k_rankap).
// ---------------------------------------------------------------------------
#define FLAG_LANE(CC, FVAR)                                                 \
  FVAR = (s_orT[0 * NCH_P + (CC)] & ~D0) | (s_orT[1 * NCH_P + (CC)] & ~D1) |\
         (s_orT[2 * NCH_P + (CC)] & ~D2) | (s_orT[3 * NCH_P + (CC)] & ~D3) |\
         (s_orT[4 * NCH_P + (CC)] & ~D4) | (s_orT[5 * NCH_P + (CC)] & ~D5) |\
         (s_orT[6 * NCH_P + (CC)] & ~D6) | (s_orT[7 * NCH_P + (CC)] & ~D7);

#define FIND_NEXT(C0, RES)                                                  \
  {                                                                         \
    const int start_ = (C0);            /* evaluate BEFORE touching RES */  \
    RES = -1;                                                               \
    for (int c_ = start_; c_ < NCHUNK; c_ += 64) {                          \
      const int cc_ = c_ + lane;                                            \
      uint32_t f_ = 0u;                                                     \
      if (cc_ < NCHUNK) { FLAG_LANE(cc_, f_); }                             \
      const unsigned long long bal_ = __ballot(f_ != 0u);                   \
      if (bal_ != 0ull) { RES = c_ + (__ffsll(bal_) - 1); break; }          \
    }                                                                       \
  }

// masks fully written to N_PAD rows; CH <= 390 -> max uint4 index
// 390*512+511 = 200,191 < N_PAD*NW/4 = 200,192: in-bounds.
#define ISSUE(CH, R0A, R0B, R1A, R1B, R2A, R2B, R3A, R3B)                   \
  {                                                                         \
    const uint4* qm_ =                                                      \
        reinterpret_cast<const uint4*>(&masks[(size_t)(CH) * CHUNK * NW]);  \
    const int l2_ = lane * 2;                                               \
    R0A = qm_[l2_];       R0B = qm_[l2_ + 1];                               \
    R1A = qm_[128 + l2_]; R1B = qm_[128 + l2_ + 1];                         \
    R2A = qm_[256 + l2_]; R2B = qm_[256 + l2_ + 1];                         \
    R3A = qm_[384 + l2_]; R3B = qm_[384 + l2_ + 1];                         \
  }

#define PENDW(VA, VB)                                                       \
    w0 = ((unsigned long long)(VA.y & ~D1) << 32) |                         \
         (unsigned long long)(uint32_t)(VA.x & ~D0);                        \
    w1 = ((unsigned long long)(VA.w & ~D3) << 32) |                         \
         (unsigned long long)(uint32_t)(VA.z & ~D2);                        \
    w2 = ((unsigned long long)(VB.y & ~D5) << 32) |                         \
         (unsigned long long)(uint32_t)(VB.x & ~D4);                        \
    w3 = ((unsigned long long)(VB.w & ~D7) << 32) |                         \
         (unsigned long long)(uint32_t)(VB.z & ~D6);

// Batch-commit round (exactness proven R14; absmax 0.0 R14-R18): pending
// lanes post claims to the epoch-stamped owner table (atomicMax -> min lane
// wins; stale epochs auto-invalid). fl = first losing lane; all pending
// lanes < fl commit together. Lazy stale-check (R18): a lane's first-pending
// changes iff its bit entered D this round. Intra-wave LDS FIFO -> no fences.
#define DRAIN64B(BASE, VA, VB)                                              \
  {                                                                         \
    unsigned long long w0, w1, w2, w3;                                      \
    PENDW(VA, VB)                                                           \
    int j_i;                                                                \
    FIRST_PEND(j_i, w0, w1, w2, w3);                                        \
    while (true) {                                                          \
      const unsigned long long bal = __ballot(j_i >= 0);                    \
      if (bal == 0ull) break;                                               \
      ++epoch;                                                              \
      const unsigned my_ = ((unsigned)epoch << 8) | (63u ^ (unsigned)lane); \
      if (j_i >= 0) atomicMax(&s_own[j_i], my_);                            \
      const bool won_ = (j_i >= 0) && (s_own[j_i] == my_);                  \
      const unsigned long long lostb = __ballot((j_i >= 0) && !won_);       \
      const int fl_ = (lostb != 0ull) ? (__ffsll(lostb) - 1) : 64;          \
      const bool com_ = won_ && (lane < fl_);                               \
      const unsigned long long cbal = __ballot(com_);                       \
      if (com_) {                                                           \
        atomicOr(&s_D[j_i >> 5], 1u << (j_i & 31));                         \
        const int pos_ = T + __popcll(cbal & ((1ull << lane) - 1ull));      \
        if (pos_ < N_LAB) s_tpi[pos_] = (BASE) + lane;                      \
      }                                                                     \
      T += __popcll(cbal);                                                  \
      D0 = s_D[0]; D1 = s_D[1]; D2 = s_D[2]; D3 = s_D[3];                   \
      D4 = s_D[4]; D5 = s_D[5]; D6 = s_D[6]; D7 = s_D[7];                   \
      if (T >= N_LAB) break;                                                \
      if (com_) {                                                           \
        j_i = -1;                              /* claimed exactly once */   \
      } else if (j_i >= 0) {                   /* lazy stale check */       \
        const uint32_t dw_ =                                                \
            (j_i < 64)  ? ((j_i < 32)  ? D0 : D1)                           \
          : (j_i < 128) ? ((j_i < 96)  ? D2 : D3)                           \
          : (j_i < 192) ? ((j_i < 160) ? D4 : D5)                           \
          :               ((j_i < 224) ? D6 : D7);                          \
        if ((dw_ >> (j_i & 31)) & 1u) {        /* stale: full recompute */  \
          PENDW(VA, VB)                                                     \
          FIRST_PEND(j_i, w0, w1, w2, w3);                                  \
        }                                                                   \
      }                                                                     \
    }                                                                       \
  }

#define COPY_BA                                                             \
  a0A = b0A; a0B = b0B; a1A = b1A; a1B = b1B;                               \
  a2A = b2A; a2B = b2B; a3A = b3A; a3B = b3B;

__global__ __launch_bounds__(256) void k_scanrank(
    const uint32_t* __restrict__ masks, const uint32_t* __restrict__ chunkOR,
    const float* __restrict__ prop,
    unsigned long long* keys, int* tp_cnt, int* ctrl, float* out) {
  __shared__ uint32_t s_orT[NW * NCH_P];       // transposed: [word][chunk]
  __shared__ uint32_t s_own[N_LAB];            // epoch-stamped owner table
  __shared__ uint32_t s_D[NW];                 // detected bits (LDS master)
  __shared__ int s_tpi[N_LAB];
  __shared__ int s_T;
  __shared__ int s_last;
  __shared__ unsigned long long s_key[N_LAB];
  __shared__ unsigned long long s_srt[N_LAB];
  __shared__ int s_hist[N_LAB + 1];
  __shared__ int s_a[N_LAB + 1];
  __shared__ int s_b[N_LAB + 1];
  __shared__ int s_p[N_LAB];
  const int t = threadIdx.x;
  const int bid = blockIdx.x;
  int* hist = &ctrl[4];

  if (bid == 0) {
    // ---- scan + sort (byte-identical to R18, proven; masks L2-warm) ----
    s_own[t] = 0u;
    if (t < NW) s_D[t] = 0u;
    for (int f = t; f < NCHUNK * NW; f += 256)
      s_orT[(f & 7) * NCH_P + (f >> 3)] = chunkOR[f];
    __syncthreads();

    if (t < 64) {
      const int lane = t;
      uint32_t D0 = 0, D1 = 0, D2 = 0, D3 = 0, D4 = 0, D5 = 0, D6 = 0, D7 = 0;
      int T = 0;
      int epoch = 0;
      uint4 a0A, a0B, a1A, a1B, a2A, a2B, a3A, a3B;
      uint4 b0A, b0B, b1A, b1B, b2A, b2B, b3A, b3B;

      int cur;
      FIND_NEXT(0, cur);
      if (cur >= 0) { ISSUE(cur, a0A, a0B, a1A, a1B, a2A, a2B, a3A, a3B); }
      while (cur >= 0) {
        int nxt;
        FIND_NEXT(cur + 1, nxt);               // superset test (pre-drain D)
        if (nxt >= 0) { ISSUE(nxt, b0A, b0B, b1A, b1B, b2A, b2B, b3A, b3B); }

        DRAIN64B(cur * CHUNK + 0,   a0A, a0B);
        DRAIN64B(cur * CHUNK + 64,  a1A, a1B);
        DRAIN64B(cur * CHUNK + 128, a2A, a2B);
        DRAIN64B(cur * CHUNK + 192, a3A, a3B);

        if (T >= N_LAB) break;                 // detected full
        while (nxt >= 0) {                     // re-validate under grown D
          uint32_t fu;
          FLAG_LANE(nxt, fu);                  // uniform addr -> broadcast
          if (fu != 0u) break;
          FIND_NEXT(nxt + 1, nxt);
          if (nxt >= 0) { ISSUE(nxt, b0A, b0B, b1A, b1B, b2A, b2B, b3A, b3B); }
        }
        cur = nxt;                             // strictly increases
        if (cur >= 0) { COPY_BA }
      }
      if (lane == 0) s_T = (T < N_LAB) ? T : N_LAB;
    }
    __syncthreads();

    // ---- TP key build + counting sort (proven). key = conf<<32 | ~idx ----
    const int T = s_T;
    unsigned long long k = ~0ull;
    if (t < T) {
      const int it = s_tpi[t];
      const unsigned cb = __float_as_uint(prop[3 * it]);
      k = ((unsigned long long)cb << 32) |
          (unsigned long long)(0xFFFFFFFFu - (unsigned)it);
    }
    s_key[t] = k;
    s_srt[t] = ~0ull;
    __syncthreads();
    int pos = 0;
    for (int s = 0; s < N_LAB; ++s) pos += (s_key[s] < k) ? 1 : 0;
    if (t < T) s_srt[pos] = k;                 // real keys distinct
    __syncthreads();
    keys[t] = s_srt[t];
    if (t == 0) tp_cnt[0] = T;
    __syncthreads();
    __threadfence();                            // release keys/tp_cnt
    if (t == 0)
      __hip_atomic_store(&ctrl[0], 1, __ATOMIC_RELEASE,
                         __HIP_MEMORY_SCOPE_AGENT);
  } else {
    // short-sleep poll: ~1.7us/poll at idle clock; jitter bounded ~2us
    if (t == 0) {
      while (__hip_atomic_load(&ctrl[0], __ATOMIC_ACQUIRE,
                               __HIP_MEMORY_SCOPE_AGENT) == 0)
        __builtin_amdgcn_s_sleep(16);
    }
    __syncthreads();
    __threadfence();                            // acquire winner's writes
  }

  // ---- rank histogram (all 128 blocks; proven exact lower_bound) ----
  s_key[t] = keys[t];
  s_hist[t] = 0;
  if (t == 0) s_hist[N_LAB] = 0;
  __syncthreads();

  for (int i = bid * 256 + t; i < N_PROP; i += RANK_BLOCKS * 256) {
    const unsigned cb = __float_as_uint(prop[3 * i]);
    const unsigned long long k =
        ((unsigned long long)cb << 32) |
        (unsigned long long)(0xFFFFFFFFu - (unsigned)i);
    int p = 0;
#pragma unroll
    for (int s = 256; s > 0; s >>= 1) {
      const int cand = p + s;
      if (cand <= N_LAB && s_key[cand - 1] < k) p = cand;
    }
    atomicAdd(&s_hist[p], 1);
  }
  __syncthreads();
  if (s_hist[t] != 0) atomicAdd(&hist[t], s_hist[t]);
  if (t == 0 && s_hist[N_LAB] != 0) atomicAdd(&hist[N_LAB], s_hist[N_LAB]);

  __threadfence();                              // release partials
  if (t == 0)
    s_last = (atomicAdd(&ctrl[1], 1) == RANK_BLOCKS - 1) ? 1 : 0;
  __syncthreads();
  if (!s_last) return;
  __threadfence();                              // acquire partials

  // ---- AP fan-in (ticket winner; exact suffix scan + bit-exact fp loop) ---
  int T = tp_cnt[0];
  T = (T < 0) ? 0 : ((T > N_LAB) ? N_LAB : T);
  s_a[t] = atomicAdd(&hist[t], 0);              // coherent read
  if (t == 0) s_a[N_LAB] = atomicAdd(&hist[N_LAB], 0);
  __syncthreads();
  int* src = s_a;
  int* dst = s_b;
#pragma unroll
  for (int s = 1; s <= N_LAB; s <<= 1) {        // exact int suffix scan
    const int v = src[t] + ((t + s <= N_LAB) ? src[t + s] : 0);
    const int v256 = (t == 0) ? src[N_LAB] : 0;
    __syncthreads();
    dst[t] = v;
    if (t == 0) dst[N_LAB] = v256;
    __syncthreads();
    int* tmp = src; src = dst; dst = tmp;
  }
  if (t < T) s_p[(T - 1) - t] = 1 + src[t + 1]; // ranks ascending
  __syncthreads();
  if (t == 0) {
    float m = 0.0f, sum = 0.0f;
    for (int i = T - 1; i >= 0; --i) {
      const float prec = (float)(i + 1) / (float)s_p[i];  // IEEE div, as ref
      m = fmaxf(m, prec);
      if (s_p[i] >= 2) sum += m * 0.00390625f;  // * (1/256), exact
    }
    out[0] = sum;
  }
}

extern "C" void kernel_launch(void* const* d_in, const int* in_sizes, int n_in,
                              void* d_out, int out_size, void* d_ws,
                              size_t ws_size, hipStream_t stream) {
  (void)in_sizes; (void)n_in; (void)out_size; (void)ws_size;
  const float* prop = (const float*)d_in[0];
  const float* lab  = (const float*)d_in[1];
  uint8_t* ws = (uint8_t*)d_ws;
  uint32_t* masks  = (uint32_t*)(ws + OFF_MASKS);
  uint32_t* chOR   = (uint32_t*)(ws + OFF_CHUNKOR);
  unsigned long long* keys = (unsigned long long*)(ws + OFF_KEYS);
  int*      tp_cnt = (int*)(ws + OFF_TPCNT);
  int*      ctrl   = (int*)(ws + OFF_CTRL);
  float*    out    = (float*)d_out;

  k_masks  <<<dim3(NCHUNK),      dim3(512), 0, stream>>>(prop, lab, masks,
                                                         chOR, ctrl);
  k_scanrank<<<dim3(RANK_BLOCKS), dim3(256), 0, stream>>>(masks, chOR, prop,
                                                          keys, tp_cnt, ctrl,
                                                          out);
}

// Round 20
// 94.037 us; speedup vs baseline: 1.2826x; 1.2826x over previous
//
#include <hip/hip_runtime.h>
#include <stdint.h>

#define N_PROP 100000
#define N_LAB  256
#define NW     8                      // 256 bits / 32
#define CHUNK  256
#define NCHUNK 391                    // ceil(100000/256)
#define NCH_P  392                    // padded stride for transposed chunkOR
#define N_PAD  (NCHUNK * CHUNK)       // 100096
#define RANK_BLOCKS 128

// d_ws byte offsets
#define OFF_MASKS   0
#define OFF_CHUNKOR (N_PAD * NW * 4)                   // 3,203,072
#define OFF_KEYS    (OFF_CHUNKOR + NCHUNK * NW * 4)    // 3,215,584
#define OFF_TPCNT   (OFF_KEYS + N_LAB * 8)
#define OFF_CTRL    (OFF_TPCNT + 16)
// ctrl ints: [2]=K3 AP ticket (zeroed by K2), [4..260]=hist (zeroed by K2)

// first pending label from 4 x u64 pending words (-1 if none)
#define FIRST_PEND(j_i, w0, w1, w2, w3)         \
  {                                             \
    j_i = -1;                                   \
    if (w3) j_i = 192 + (__ffsll(w3) - 1);      \
    if (w2) j_i = 128 + (__ffsll(w2) - 1);      \
    if (w1) j_i = 64 + (__ffsll(w1) - 1);       \
    if (w0) j_i = (__ffsll(w0) - 1);            \
  }

// ---------------------------------------------------------------------------
// Kernel 1 (field-proven bit-exact, R15/R16): per-proposal IoU>0.5 masks +
// per-chunk OR. 512 threads: 2 threads/proposal, each covering 128 labels
// (disjoint half-mask uint4 stores).
//
// EXACT div-free predicate (validated absmax 0.0 R15-R18): reference computes
// fl(i/u) > 0.5 with i>=0, u>0.
//   fl(r) > 0.5  <=>  r > 0.5 + 2^-26  <=>  2i - u > u * 2^-25 (exact reals)
// i <= blen <= u (RN monotone). For i in [u/4, u]: i - u/2 is Sterbenz-exact
// so fma(2,i,-u) is EXACT; u*2^-25 is an exact exponent shift; compare exact.
// For i < u/4: lhs <= -u/2 < rhs: false, matching r < 0.5.
// ---------------------------------------------------------------------------
__global__ __launch_bounds__(512) void k_masks(
    const float* __restrict__ prop, const float* __restrict__ lab,
    uint32_t* __restrict__ masks, uint32_t* __restrict__ chunkOR) {
  __shared__ float4 s_lab[N_LAB];     // (bmin, bmax, blen, 0)
  __shared__ uint32_t s_or[NW];
  const int t = threadIdx.x;
  const int h = t >> 8;               // label half: 0 -> [0,128), 1 -> [128,256)
  const int q = t & 255;              // proposal slot within chunk
  if (t < N_LAB) {
    const float bmn = lab[2 * t], bmx = lab[2 * t + 1];
    s_lab[t] = make_float4(bmn, bmx, bmx - bmn, 0.0f);
  }
  if (t < NW) s_or[t] = 0u;
  __syncthreads();

  const int i = blockIdx.x * 256 + q;  // < N_PAD always
  uint32_t m0 = 0u, m1 = 0u, m2 = 0u, m3 = 0u;

  if (i < N_PROP) {
    const float ps = prop[3 * i + 1], pe = prop[3 * i + 2];
    const float amin = ps / 25.0f;     // IEEE div, as reference
    const float amax = pe / 25.0f;
    const float alen = amax - amin;
    const int j0 = h << 7;
#pragma unroll 4
    for (int jj = 0; jj < 128; ++jj) {
      const float4 L = s_lab[j0 + jj];
      float inter = fminf(amax, L.y) - fmaxf(amin, L.x);
      inter = fmaxf(inter, 0.0f);
      const float uni = (alen - inter) + L.z;
      const bool pred =
          __builtin_fmaf(2.0f, inter, -uni) > uni * 0x1p-25f;  // exact
      if (pred) {
        const uint32_t b = 1u << (jj & 31);
        const int w = jj >> 5;
        m0 |= (w == 0) ? b : 0u;  m1 |= (w == 1) ? b : 0u;
        m2 |= (w == 2) ? b : 0u;  m3 |= (w == 3) ? b : 0u;
      }
    }
  }

  // disjoint half-mask store (words h*4 .. h*4+3); pad rows stay zero
  *reinterpret_cast<uint4*>(&masks[(size_t)i * NW + h * 4]) =
      make_uint4(m0, m1, m2, m3);

  if (m0 | m1 | m2 | m3) {
    const int wb = h * 4;
    if (m0) atomicOr(&s_or[wb + 0], m0);
    if (m1) atomicOr(&s_or[wb + 1], m1);
    if (m2) atomicOr(&s_or[wb + 2], m2);
    if (m3) atomicOr(&s_or[wb + 3], m3);
  }
  __syncthreads();
  if (t < NW) chunkOR[blockIdx.x * NW + t] = s_or[t];
}

// ---------------------------------------------------------------------------
// Kernel 2 (R16, field-proven absmax 0.0, 94.3 us config): exact sequential
// greedy scan (wave 0, batch-commit rounds, no intra-wave fences) + TP key
// sort (all 256 threads). Claim semantics proven vs reference: proposals
// evaluated exactly once in ascending index order; a proposal claims the
// first label of (mask & ~detected), then stops.
// ---------------------------------------------------------------------------
#define FLAG_LANE(CC, FVAR)                                                 \
  FVAR = (s_orT[0 * NCH_P + (CC)] & ~D0) | (s_orT[1 * NCH_P + (CC)] & ~D1) |\
         (s_orT[2 * NCH_P + (CC)] & ~D2) | (s_orT[3 * NCH_P + (CC)] & ~D3) |\
         (s_orT[4 * NCH_P + (CC)] & ~D4) | (s_orT[5 * NCH_P + (CC)] & ~D5) |\
         (s_orT[6 * NCH_P + (CC)] & ~D6) | (s_orT[7 * NCH_P + (CC)] & ~D7);

#define FIND_NEXT(C0, RES)                                                  \
  {                                                                         \
    const int start_ = (C0);            /* evaluate BEFORE touching RES */  \
    RES = -1;                                                               \
    for (int c_ = start_; c_ < NCHUNK; c_ += 64) {                          \
      const int cc_ = c_ + lane;                                            \
      uint32_t f_ = 0u;                                                     \
      if (cc_ < NCHUNK) { FLAG_LANE(cc_, f_); }                             \
      const unsigned long long bal_ = __ballot(f_ != 0u);                   \
      if (bal_ != 0ull) { RES = c_ + (__ffsll(bal_) - 1); break; }          \
    }                                                                       \
  }

// masks fully written to N_PAD rows; CH <= 390 -> max uint4 index
// 390*512+511 = 200,191 < N_PAD*NW/4 = 200,192: in-bounds.
#define ISSUE(CH, R0A, R0B, R1A, R1B, R2A, R2B, R3A, R3B)                   \
  {                                                                         \
    const uint4* qm_ =                                                      \
        reinterpret_cast<const uint4*>(&masks[(size_t)(CH) * CHUNK * NW]);  \
    const int l2_ = lane * 2;                                               \
    R0A = qm_[l2_];       R0B = qm_[l2_ + 1];                               \
    R1A = qm_[128 + l2_]; R1B = qm_[128 + l2_ + 1];                         \
    R2A = qm_[256 + l2_]; R2B = qm_[256 + l2_ + 1];                         \
    R3A = qm_[384 + l2_]; R3B = qm_[384 + l2_ + 1];                         \
  }

#define PENDW(VA, VB)                                                       \
    w0 = ((unsigned long long)(VA.y & ~D1) << 32) |                         \
         (unsigned long long)(uint32_t)(VA.x & ~D0);                        \
    w1 = ((unsigned long long)(VA.w & ~D3) << 32) |                         \
         (unsigned long long)(uint32_t)(VA.z & ~D2);                        \
    w2 = ((unsigned long long)(VB.y & ~D5) << 32) |                         \
         (unsigned long long)(uint32_t)(VB.x & ~D4);                        \
    w3 = ((unsigned long long)(VB.w & ~D7) << 32) |                         \
         (unsigned long long)(uint32_t)(VB.z & ~D6);

// Batch-commit round (exactness proven R14; absmax 0.0 R14-R18): pending
// lanes post claims to the epoch-stamped owner table (atomicMax -> min lane
// wins; stale epochs auto-invalid). fl = first losing lane; all pending
// lanes < fl commit together (pairwise-distinct claims; earlier commits
// cannot alter a later committed lane's first-pending; induction gives each
// pending lane exactly its sequential D). >=1 commit/round guaranteed.
// Intra-wave LDS FIFO order -> no fences needed (R16-proven).
#define DRAIN64B(BASE, VA, VB)                                              \
  {                                                                         \
    unsigned long long w0, w1, w2, w3;                                      \
    PENDW(VA, VB)                                                           \
    int j_i;                                                                \
    FIRST_PEND(j_i, w0, w1, w2, w3);                                        \
    while (true) {                                                          \
      const unsigned long long bal = __ballot(j_i >= 0);                    \
      if (bal == 0ull) break;                                               \
      ++epoch;                                                              \
      const unsigned my_ = ((unsigned)epoch << 8) | (63u ^ (unsigned)lane); \
      if (j_i >= 0) atomicMax(&s_own[j_i], my_);                            \
      const bool won_ = (j_i >= 0) && (s_own[j_i] == my_);                  \
      const unsigned long long lostb = __ballot((j_i >= 0) && !won_);       \
      const int fl_ = (lostb != 0ull) ? (__ffsll(lostb) - 1) : 64;          \
      const bool com_ = won_ && (lane < fl_);                               \
      const unsigned long long cbal = __ballot(com_);                       \
      if (com_) {                                                           \
        atomicOr(&s_D[j_i >> 5], 1u << (j_i & 31));                         \
        const int pos_ = T + __popcll(cbal & ((1ull << lane) - 1ull));      \
        if (pos_ < N_LAB) s_tpi[pos_] = (BASE) + lane;                      \
      }                                                                     \
      T += __popcll(cbal);                                                  \
      D0 = s_D[0]; D1 = s_D[1]; D2 = s_D[2]; D3 = s_D[3];                   \
      D4 = s_D[4]; D5 = s_D[5]; D6 = s_D[6]; D7 = s_D[7];                   \
      if (T >= N_LAB) break;                                                \
      if (com_) {                                                           \
        j_i = -1;                              /* claimed exactly once */   \
      } else if (j_i >= 0) {                   /* recompute under new D */  \
        PENDW(VA, VB)                                                       \
        FIRST_PEND(j_i, w0, w1, w2, w3);                                    \
      }                                                                     \
    }                                                                       \
  }

#define COPY_BA                                                             \
  a0A = b0A; a0B = b0B; a1A = b1A; a1B = b1B;                               \
  a2A = b2A; a2B = b2B; a3A = b3A; a3B = b3B;

__global__ __launch_bounds__(256) void k_scansort(
    const uint32_t* __restrict__ masks, const uint32_t* __restrict__ chunkOR,
    const float* __restrict__ prop,
    unsigned long long* __restrict__ keys, int* __restrict__ tp_cnt,
    int* __restrict__ ctrl) {
  __shared__ uint32_t s_orT[NW * NCH_P];       // transposed: [word][chunk]
  __shared__ uint32_t s_own[N_LAB];            // epoch-stamped owner table
  __shared__ uint32_t s_D[NW];                 // detected bits (LDS master)
  __shared__ int s_tpi[N_LAB];
  __shared__ int s_T;
  __shared__ unsigned long long s_key[N_LAB];
  __shared__ unsigned long long s_srt[N_LAB];
  const int t = threadIdx.x;

  // zero K3's ticket + hist (single block, runs before K3 in-stream)
  if (t == 0) ctrl[2] = 0;
  for (int z = t; z <= N_LAB; z += 256) ctrl[4 + z] = 0;
  s_own[t] = 0u;
  if (t < NW) s_D[t] = 0u;

  // stage chunkOR transposed (f = c*8+w -> s_orT[w][c]); coalesced reads.
  for (int f = t; f < NCHUNK * NW; f += 256)
    s_orT[(f & 7) * NCH_P + (f >> 3)] = chunkOR[f];
  __syncthreads();

  if (t < 64) {
    const int lane = t;
    uint32_t D0 = 0, D1 = 0, D2 = 0, D3 = 0, D4 = 0, D5 = 0, D6 = 0, D7 = 0;
    int T = 0;
    int epoch = 0;
    uint4 a0A, a0B, a1A, a1B, a2A, a2B, a3A, a3B;   // current chunk masks
    uint4 b0A, b0B, b1A, b1B, b2A, b2B, b3A, b3B;   // prefetched next chunk

    int cur;
    FIND_NEXT(0, cur);
    if (cur >= 0) { ISSUE(cur, a0A, a0B, a1A, a1B, a2A, a2B, a3A, a3B); }
    while (cur >= 0) {
      int nxt;
      FIND_NEXT(cur + 1, nxt);                 // superset test (pre-drain D)
      if (nxt >= 0) { ISSUE(nxt, b0A, b0B, b1A, b1B, b2A, b2B, b3A, b3B); }

      DRAIN64B(cur * CHUNK + 0,   a0A, a0B);
      DRAIN64B(cur * CHUNK + 64,  a1A, a1B);
      DRAIN64B(cur * CHUNK + 128, a2A, a2B);
      DRAIN64B(cur * CHUNK + 192, a3A, a3B);

      if (T >= N_LAB) break;                   // detected full: no more claims
      while (nxt >= 0) {                       // re-validate under grown D
        uint32_t fu;
        FLAG_LANE(nxt, fu);                    // uniform addr -> broadcast
        if (fu != 0u) break;
        FIND_NEXT(nxt + 1, nxt);
        if (nxt >= 0) { ISSUE(nxt, b0A, b0B, b1A, b1B, b2A, b2B, b3A, b3B); }
      }
      cur = nxt;                               // strictly increases
      if (cur >= 0) { COPY_BA }
    }
    if (lane == 0) s_T = (T < N_LAB) ? T : N_LAB;
  }
  __syncthreads();

  // ---- TP key build + counting sort (all 256 threads; proven) ----
  // key = conf_bits<<32 | (0xFFFFFFFF - idx): exactly the reference's stable
  // argsort(-conf) priority (conf >= 0; ties -> lower idx first).
  const int T = s_T;
  unsigned long long k = ~0ull;
  if (t < T) {
    const int it = s_tpi[t];
    const unsigned cb = __float_as_uint(prop[3 * it]);
    k = ((unsigned long long)cb << 32) |
        (unsigned long long)(0xFFFFFFFFu - (unsigned)it);
  }
  s_key[t] = k;
  s_srt[t] = ~0ull;
  __syncthreads();
  int pos = 0;
  for (int s = 0; s < N_LAB; ++s) pos += (s_key[s] < k) ? 1 : 0;
  if (t < T) s_srt[pos] = k;                   // real keys distinct
  __syncthreads();
  keys[t] = s_srt[t];
  if (t == 0) tp_cnt[0] = T;
}

// ---------------------------------------------------------------------------
// Kernel 3 (R9/R11/R14-R16, proven): rank histogram (128 blocks) + last-block
// AP fan-in. p_i = #{sorted TP keys < key_i} (exact 9-step lower_bound).
// AP = (1/256) * sum_{i: p_i >= 2} max_{j>=i} (j / p_j); rank-1 excluded.
// ---------------------------------------------------------------------------
__global__ __launch_bounds__(256) void k_rankap(
    const float* __restrict__ prop, const unsigned long long* __restrict__ keys,
    const int* __restrict__ tp_cnt, int* ctrl, float* __restrict__ out) {
  __shared__ unsigned long long s_key[N_LAB];
  __shared__ int s_hist[N_LAB + 1];
  __shared__ int s_last;
  __shared__ int s_a[N_LAB + 1];
  __shared__ int s_b[N_LAB + 1];
  __shared__ int s_p[N_LAB];
  const int t = threadIdx.x;
  int* hist = &ctrl[4];
  s_key[t] = keys[t];
  s_hist[t] = 0;
  if (t == 0) s_hist[N_LAB] = 0;
  __syncthreads();

  for (int i = blockIdx.x * 256 + t; i < N_PROP; i += RANK_BLOCKS * 256) {
    const unsigned cb = __float_as_uint(prop[3 * i]);
    const unsigned long long k =
        ((unsigned long long)cb << 32) |
        (unsigned long long)(0xFFFFFFFFu - (unsigned)i);
    int p = 0;
#pragma unroll
    for (int s = 256; s > 0; s >>= 1) {
      const int cand = p + s;
      if (cand <= N_LAB && s_key[cand - 1] < k) p = cand;
    }
    atomicAdd(&s_hist[p], 1);
  }
  __syncthreads();
  if (s_hist[t] != 0) atomicAdd(&hist[t], s_hist[t]);
  if (t == 0 && s_hist[N_LAB] != 0) atomicAdd(&hist[N_LAB], s_hist[N_LAB]);

  __threadfence();                              // release partials
  if (t == 0)
    s_last = (atomicAdd(&ctrl[2], 1) == RANK_BLOCKS - 1) ? 1 : 0;
  __syncthreads();
  if (!s_last) return;
  __threadfence();                              // acquire partials

  int T = tp_cnt[0];
  T = (T < 0) ? 0 : ((T > N_LAB) ? N_LAB : T);
  s_a[t] = atomicAdd(&hist[t], 0);              // coherent read
  if (t == 0) s_a[N_LAB] = atomicAdd(&hist[N_LAB], 0);
  __syncthreads();
  int* src = s_a;
  int* dst = s_b;
#pragma unroll
  for (int s = 1; s <= N_LAB; s <<= 1) {        // exact int suffix scan
    const int v = src[t] + ((t + s <= N_LAB) ? src[t + s] : 0);
    const int v256 = (t == 0) ? src[N_LAB] : 0;
    __syncthreads();
    dst[t] = v;
    if (t == 0) dst[N_LAB] = v256;
    __syncthreads();
    int* tmp = src; src = dst; dst = tmp;
  }
  if (t < T) s_p[(T - 1) - t] = 1 + src[t + 1]; // ranks ascending
  __syncthreads();
  if (t == 0) {
    float m = 0.0f, sum = 0.0f;
    for (int i = T - 1; i >= 0; --i) {
      const float prec = (float)(i + 1) / (float)s_p[i];  // IEEE div, as ref
      m = fmaxf(m, prec);
      if (s_p[i] >= 2) sum += m * 0.00390625f;  // * (1/256), exact
    }
    out[0] = sum;
  }
}

extern "C" void kernel_launch(void* const* d_in, const int* in_sizes, int n_in,
                              void* d_out, int out_size, void* d_ws,
                              size_t ws_size, hipStream_t stream) {
  (void)in_sizes; (void)n_in; (void)out_size; (void)ws_size;
  const float* prop = (const float*)d_in[0];
  const float* lab  = (const float*)d_in[1];
  uint8_t* ws = (uint8_t*)d_ws;
  uint32_t* masks  = (uint32_t*)(ws + OFF_MASKS);
  uint32_t* chOR   = (uint32_t*)(ws + OFF_CHUNKOR);
  unsigned long long* keys = (unsigned long long*)(ws + OFF_KEYS);
  int*      tp_cnt = (int*)(ws + OFF_TPCNT);
  int*      ctrl   = (int*)(ws + OFF_CTRL);
  float*    out    = (float*)d_out;

  k_masks   <<<dim3(NCHUNK),      dim3(512), 0, stream>>>(prop, lab, masks, chOR);
  k_scansort<<<dim3(1),           dim3(256), 0, stream>>>(masks, chOR, prop,
                                                          keys, tp_cnt, ctrl);
  k_rankap  <<<dim3(RANK_BLOCKS), dim3(256), 0, stream>>>(prop, keys, tp_cnt,
                                                          ctrl, out);
}